// Round 1
// 320.339 us; speedup vs baseline: 1.0031x; 1.0031x over previous
//
#include <hip/hip_runtime.h>

// RoPE2D cos/sin table generator — float32.
// Output: [cos_2d (rows*dim)] ++ [sin_2d (rows*dim)], rows = H*W, dim = dimx+dimy.
// Row p = y*W + x. Channel c:
//   c in [0, dimx):   val = trig(x * ifx[c mod (dimx/2)])
//   c in [dimx, dim): val = trig(y * ify[(c-dimx) mod (dimy/2)])
//
// Strategy (fast path, dimx=dimy=64): only 2*(W+H)*32 trig values are unique
// (512 KB for 512x512) but the output is 256 MiB. Phase 1 computes the unique
// values once into d_ws; phase 2 is a pure table-broadcast + dense dwordx4
// store kernel (zero transcendentals per output element) that should run at
// the HBM write roofline.

typedef __attribute__((ext_vector_type(4))) float float4v;

#define TABP  4096            // max positions cached per table
#define TABSZ (TABP * 32)     // floats per table (pos-major, 32 freqs each)
// ws layout: [cosx | sinx | cosy | siny], each TABSZ floats = 512 KB, 2 MB total.

// ---------------------------------------------------------------------------
// Phase 1: unique trig values. t = pos*32 + k. 131072 threads, ~微s.
__global__ __launch_bounds__(256) void rope2d_tables(
    const float* __restrict__ ifx,
    const float* __restrict__ ify,
    float* __restrict__ ws)
{
    const int t = blockIdx.x * blockDim.x + threadIdx.x;
    if (t >= TABSZ) return;
    const float fp = (float)(t >> 5);   // position
    const int k = t & 31;               // freq index
    float sx, cx, sy, cy;
    __sincosf(fp * ifx[k], &sx, &cx);
    __sincosf(fp * ify[k], &sy, &cy);
    ws[t]             = cx;
    ws[TABSZ + t]     = sx;
    ws[2 * TABSZ + t] = cy;
    ws[3 * TABSZ + t] = sy;
}

// ---------------------------------------------------------------------------
// Phase 2: one thread = 4 contiguous output floats = one dwordx4 gather from
// the L2-resident table + one dense dwordx4 store. No trig.
__global__ __launch_bounds__(256) void rope2d_fill(
    const float* __restrict__ ws,
    const float* __restrict__ ifx,   // fallback only (pos >= TABP)
    const float* __restrict__ ify,
    const int* __restrict__ wptr,
    float* __restrict__ out,
    int rows)
{
    const int idx = blockIdx.x * blockDim.x + threadIdx.x;
    const int total4 = rows << 6;            // 2*rows*128/4
    if (idx >= total4) return;

    const int e = idx << 2;                  // element offset in flat output
    const int half = rows << 7;              // rows*128
    const bool is_sin = e >= half;           // block-uniform (half % 1024 == 0)
    const int e2 = is_sin ? e - half : e;

    const int p  = e2 >> 7;                  // row
    const int ch = e2 & 127;                 // first channel of the 4 (4-aligned)

    const int W = *wptr;
    int xw, yh;
    if ((W & (W - 1)) == 0) {
        const int s = __ffs(W) - 1;
        xw = p & (W - 1);
        yh = p >> s;
    } else {
        xw = p % W;
        yh = p / W;
    }

    // quadrants: ch [0,64) -> x-table, [64,128) -> y-table; fidx = ch & 31
    const bool use_x = ch < 64;
    const int posi = use_x ? xw : yh;

    float4v v;
    if (posi < TABP) {
        // table index: [cosx, sinx, cosy, siny]
        const int tsel = (is_sin ? 1 : 0) | (use_x ? 0 : 2);
        const float* tab = ws + (size_t)tsel * TABSZ;
        v = *reinterpret_cast<const float4v*>(tab + ((posi << 5) + (ch & 31)));
    } else {
        // giant-H/W fallback: compute directly (never taken for 512x512)
        const float pos = (float)posi;
        const float* ft = use_x ? ifx : ify;
        const float4v fr = *reinterpret_cast<const float4v*>(ft + (ch & 31));
#pragma unroll
        for (int i = 0; i < 4; ++i) {
            float s, c;
            __sincosf(pos * fr[i], &s, &c);
            v[i] = is_sin ? s : c;
        }
    }

    *reinterpret_cast<float4v*>(out + e) = v;    // dense dwordx4, lanes contiguous
}

// ---------------------------------------------------------------------------
// Legacy single-kernel fast path (fallback when d_ws is unavailable/too small).
__global__ __launch_bounds__(256) void rope2d_fast(
    const float* __restrict__ ifx,
    const float* __restrict__ ify,
    const int* __restrict__ wptr,
    float* __restrict__ out,
    int rows)
{
    const int idx = blockIdx.x * blockDim.x + threadIdx.x;
    const int total4 = rows << 6;
    if (idx >= total4) return;

    const int e = idx << 2;
    const int half = rows << 7;
    const bool is_sin = e >= half;
    const int e2 = is_sin ? e - half : e;

    const int p  = e2 >> 7;
    const int ch = e2 & 127;

    const int W = *wptr;
    int xw, yh;
    if ((W & (W - 1)) == 0) {
        const int s = __ffs(W) - 1;
        xw = p & (W - 1);
        yh = p >> s;
    } else {
        xw = p % W;
        yh = p / W;
    }

    const bool use_x = ch < 64;
    const float pos = use_x ? (float)xw : (float)yh;
    const float* tab = use_x ? ifx : ify;
    const float4v fr = *reinterpret_cast<const float4v*>(tab + (ch & 31));

    float4v v;
#pragma unroll
    for (int i = 0; i < 4; ++i) {
        const float f = pos * fr[i];
        v[i] = is_sin ? __sinf(f) : __cosf(f);
    }

    *reinterpret_cast<float4v*>(out + e) = v;
}

// ---------------------------------------------------------------------------
// Generic path: arbitrary dimx/dimy (scalar per element).
__global__ __launch_bounds__(256) void rope2d_generic(
    const float* __restrict__ ifx,
    const float* __restrict__ ify,
    const int* __restrict__ wptr,
    float* __restrict__ out,
    int rows, int dimx, int dimy)
{
    const int dim = dimx + dimy;
    const long long total = 2LL * rows * dim;
    const long long e = (long long)(blockIdx.x * blockDim.x + threadIdx.x);
    if (e >= total) return;

    const long long halfo = (long long)rows * dim;
    const bool is_sin = e >= halfo;
    const long long e2 = is_sin ? e - halfo : e;
    const int p  = (int)(e2 / dim);
    const int ch = (int)(e2 % dim);

    const int W = *wptr;
    const int xw = p % W, yh = p / W;

    float pos, f;
    if (ch < dimx) { pos = (float)xw; f = ifx[ch % (dimx >> 1)]; }
    else           { pos = (float)yh; f = ify[(ch - dimx) % (dimy >> 1)]; }
    const float ang = pos * f;
    out[e] = is_sin ? __sinf(ang) : __cosf(ang);
}

extern "C" void kernel_launch(void* const* d_in, const int* in_sizes, int n_in,
                              void* d_out, int out_size, void* d_ws, size_t ws_size,
                              hipStream_t stream) {
    // inputs: [0]=x (f32, dtype-only), [1]=inv_freq_x (f32), [2]=inv_freq_y (f32),
    //         [3]=height (int32), [4]=width (int32)
    const float* ifx = (const float*)d_in[1];
    const float* ify = (const float*)d_in[2];
    const int* wptr  = (const int*)d_in[4];
    float* out = (float*)d_out;

    const int dimx = 2 * in_sizes[1];      // 64
    const int dimy = 2 * in_sizes[2];      // 64
    const int dim  = dimx + dimy;          // 128
    const int rows = in_sizes[0] / dim;    // H*W = 262144

    const size_t ws_needed = (size_t)4 * TABSZ * sizeof(float);  // 2 MB

    if (dimx == 64 && dimy == 64) {
        if (d_ws != nullptr && ws_size >= ws_needed) {
            // Phase 1: unique trig tables (131072 threads).
            float* ws = (float*)d_ws;
            const int tb = 256;
            const int tg = (TABSZ + tb - 1) / tb;                // 512 blocks
            rope2d_tables<<<tg, tb, 0, stream>>>(ifx, ify, ws);
            // Phase 2: pure broadcast-store at write roofline.
            const int total4 = rows << 6;                        // 16,777,216
            const int block = 256;
            const int grid = (total4 + block - 1) / block;       // 65,536
            rope2d_fill<<<grid, block, 0, stream>>>(ws, ifx, ify, wptr, out, rows);
        } else {
            const int total4 = rows << 6;
            const int block = 256;
            const int grid = (total4 + block - 1) / block;
            rope2d_fast<<<grid, block, 0, stream>>>(ifx, ify, wptr, out, rows);
        }
    } else {
        const long long total = 2LL * rows * dim;
        const int block = 256;
        const int grid = (int)((total + block - 1) / block);
        rope2d_generic<<<grid, block, 0, stream>>>(ifx, ify, wptr, out, rows, dimx, dimy);
    }
}